// Round 16
// baseline (392.532 us; speedup 1.0000x reference)
//
#include <hip/hip_runtime.h>
#include <hip/hip_cooperative_groups.h>

namespace cg = cooperative_groups;

#define N_NODES 50000
#define N_EDGES 800000
#define IN_DIM  256
#define OUT_DIM 64
#define BINW    64                                 // dst nodes per bin
#define NBINS   1024                               // power-of-2 table size
#define NBINS_USED ((N_NODES + BINW - 1) / BINW)   // 782
#define NCHUNK  896                                // partition chunks (= grid)
#define CH4     ((N_EDGES / 4 + NCHUNK - 1) / NCHUNK)  // 224 int4 per chunk
#define NB_GEMM ((N_NODES + 63) / 64)              // 782
#define GRID    896
#define LCSRCAP 2048                               // per-bin LDS csr cap (mean 1024, sigma 32)

typedef _Float16 f16;
typedef __attribute__((ext_vector_type(2))) __fp16 hf16x2;   // cvt_pkrtz native type
typedef __attribute__((ext_vector_type(4))) _Float16 f16x4;
typedef __attribute__((ext_vector_type(8))) _Float16 f16x8;
typedef __attribute__((ext_vector_type(4))) float f32x4;

__device__ __forceinline__ unsigned int pack_sw(int s, float w) {
    f16 hw = (f16)w;
    unsigned short us;
    __builtin_memcpy(&us, &hw, 2);
    return ((unsigned int)s << 16) | us;
}
__device__ __forceinline__ float unpack_w(unsigned int e) {
    unsigned short us = (unsigned short)(e & 0xffffu);
    f16 hw;
    __builtin_memcpy(&hw, &us, 2);
    return (float)hw;
}

// ---------------- the single cooperative kernel ----------------

__global__ __launch_bounds__(256, 4) void k_all(const float* __restrict__ h,
                                                const float* __restrict__ W,
                                                const float* __restrict__ Wa,
                                                const int* __restrict__ src,
                                                const int* __restrict__ dst,
                                                f16* __restrict__ z,
                                                f16* __restrict__ Wh,
                                                float* __restrict__ a_src,
                                                float* __restrict__ a_dst,
                                                int* __restrict__ base,
                                                int* __restrict__ binTotal,
                                                int* __restrict__ binStartG,
                                                int* __restrict__ ebuf,
                                                float* __restrict__ out) {
    cg::grid_group grid = cg::this_grid();

    __shared__ union {
        int hist[NBINS];                                       // ph1 (4 KB)
        struct { int wtot[4]; int wexc[4]; } sc;               // ph2
        struct { int binStart[NBINS]; int cursor[NBINS]; } pl; // ph3 place (8 KB)
        struct {
            int cnt[BINW]; int rb[BINW]; int cur[BINW]; float adl[BINW];
            unsigned int lcsr[LCSRCAP];
        } ag;                                                  // ph4 (9 KB)
    } sh;

    const int g    = blockIdx.x;
    const int t    = threadIdx.x;
    const int lane = t & 63;
    const int wid  = t >> 6;

    // ======== phase 1: W->f16 prep (blocks 0..15) + per-chunk histogram ========
    if (g < 16) {
        int idx = g * 256 + t;                    // 4096 float4s total
        float4 v = ((const float4*)W)[idx];
        f16x4 p = { (f16)v.x, (f16)v.y, (f16)v.z, (f16)v.w };
        ((f16x4*)Wh)[idx] = p;
    }
    for (int b = t; b < NBINS; b += 256) sh.hist[b] = 0;
    __syncthreads();
    {
        const int s4 = g * CH4;
        const int e4 = min(s4 + CH4, N_EDGES / 4);
        for (int i4 = s4 + t; i4 < e4; i4 += 256) {
            int4 dv = ((const int4*)dst)[i4];
            atomicAdd(&sh.hist[dv.x >> 6], 1);    // LDS atomics only
            atomicAdd(&sh.hist[dv.y >> 6], 1);
            atomicAdd(&sh.hist[dv.z >> 6], 1);
            atomicAdd(&sh.hist[dv.w >> 6], 1);
        }
    }
    __syncthreads();
    for (int b = t; b < NBINS; b += 256) base[g * NBINS + b] = sh.hist[b];

    grid.sync();

    // ======== phase 2: column scan (blocks 0..511, 2 bins each) ========
    // base[c][b] <- exclusive prefix over chunks; binTotal[b] = column total
    if (g < 512) {
        #pragma unroll
        for (int bb = 0; bb < 2; ++bb) {
            const int b = g + bb * 512;
            int v[4]; int s = 0;
            const int q0 = t * 4;
            #pragma unroll
            for (int j = 0; j < 4; ++j) {
                int q = q0 + j;
                v[j] = (q < NCHUNK) ? base[q * NBINS + b] : 0;
                s += v[j];
            }
            int incl = s;
            #pragma unroll
            for (int off = 1; off < 64; off <<= 1) {
                int u = __shfl_up(incl, off);
                if (lane >= off) incl += u;
            }
            if (lane == 63) sh.sc.wtot[wid] = incl;
            __syncthreads();
            if (t == 0) {
                int run = 0;
                #pragma unroll
                for (int w2 = 0; w2 < 4; ++w2) { sh.sc.wexc[w2] = run; run += sh.sc.wtot[w2]; }
            }
            __syncthreads();
            int excl = incl - s + sh.sc.wexc[wid];
            int running = excl;
            #pragma unroll
            for (int j = 0; j < 4; ++j) {
                int q = q0 + j;
                if (q < NCHUNK) { base[q * NBINS + b] = running; running += v[j]; }
            }
            if (t == 255) binTotal[b] = excl + s;   // grand total
            __syncthreads();
        }
    }

    grid.sync();

    // ======== phase 3: GEMM (784 blocks) ∥ place scatter (112 blocks) ========
    if ((g & 7) == 7) {
        // ---- place role: block p handles chunks p*8 .. p*8+7 ----
        const int p = g >> 3;
        if (t < 64) {                              // binStart = scan of binTotal
            int loc[16]; int s = 0;
            #pragma unroll
            for (int j = 0; j < 16; ++j) { loc[j] = binTotal[t * 16 + j]; s += loc[j]; }
            int incl = s;
            #pragma unroll
            for (int off = 1; off < 64; off <<= 1) {
                int u = __shfl_up(incl, off);
                if (t >= off) incl += u;
            }
            int run = incl - s;
            #pragma unroll
            for (int j = 0; j < 16; ++j) { sh.pl.binStart[t * 16 + j] = run; run += loc[j]; }
        }
        __syncthreads();
        if (g == 7) {                              // publish for phase 4
            for (int b = t; b < NBINS; b += 256) binStartG[b] = sh.pl.binStart[b];
        }
        for (int c = p * 8; c < p * 8 + 8; ++c) {
            for (int b = t; b < NBINS; b += 256)
                sh.pl.cursor[b] = sh.pl.binStart[b] + base[c * NBINS + b];
            __syncthreads();
            const int s4 = c * CH4;
            const int e4 = min(s4 + CH4, N_EDGES / 4);
            for (int i4 = s4 + t; i4 < e4; i4 += 256) {
                int4 dv = ((const int4*)dst)[i4];
                int4 sv = ((const int4*)src)[i4];
                int slot;
                slot = atomicAdd(&sh.pl.cursor[dv.x >> 6], 1); ebuf[slot] = (sv.x << 6) | (dv.x & 63);
                slot = atomicAdd(&sh.pl.cursor[dv.y >> 6], 1); ebuf[slot] = (sv.y << 6) | (dv.y & 63);
                slot = atomicAdd(&sh.pl.cursor[dv.z >> 6], 1); ebuf[slot] = (sv.z << 6) | (dv.z & 63);
                slot = atomicAdd(&sh.pl.cursor[dv.w >> 6], 1); ebuf[slot] = (sv.w << 6) | (dv.w & 63);
            }
            __syncthreads();
        }
    } else {
        // ---- GEMM role (LDS-free, R12-proven) ----
        const int gemm_id = g - (g >> 3);
        if (gemm_id < NB_GEMM) {
            const int row0  = gemm_id * 64;
            const int cl    = lane & 15;
            const int khalf = lane >> 4;

            int arow = row0 + wid * 16 + cl;
            if (arow >= N_NODES) arow = N_NODES - 1;   // tail clamp (store guarded)
            const float* hrow = h + (size_t)arow * IN_DIM;

            f32x4 acc[4] = {};

            #pragma unroll 4
            for (int kc = 0; kc < IN_DIM; kc += 32) {
                const int k0 = kc + khalf * 8;
                float4 va = *(const float4*)&hrow[k0];
                float4 vb = *(const float4*)&hrow[k0 + 4];
                union { hf16x2 h2[4]; f16x8 h8; } ua;
                ua.h2[0] = __builtin_amdgcn_cvt_pkrtz(va.x, va.y);
                ua.h2[1] = __builtin_amdgcn_cvt_pkrtz(va.z, va.w);
                ua.h2[2] = __builtin_amdgcn_cvt_pkrtz(vb.x, vb.y);
                ua.h2[3] = __builtin_amdgcn_cvt_pkrtz(vb.z, vb.w);
                f16x8 a = ua.h8;
                #pragma unroll
                for (int ct = 0; ct < 4; ++ct) {
                    const int col = ct * 16 + cl;
                    f16x8 b = *(const f16x8*)&Wh[col * 256 + k0];
                    acc[ct] = __builtin_amdgcn_mfma_f32_16x16x32_f16(a, b, acc[ct], 0, 0, 0);
                }
            }

            const int rbase = row0 + wid * 16 + khalf * 4;
            #pragma unroll
            for (int ct = 0; ct < 4; ++ct) {
                #pragma unroll
                for (int r = 0; r < 4; ++r) {
                    int row = rbase + r;
                    if (row < N_NODES)
                        z[(size_t)row * OUT_DIM + ct * 16 + cl] = (f16)acc[ct][r];
                }
            }

            float wa1[4], wa2[4];
            #pragma unroll
            for (int ct = 0; ct < 4; ++ct) {
                wa1[ct] = Wa[ct * 16 + cl];
                wa2[ct] = Wa[64 + ct * 16 + cl];
            }
            #pragma unroll
            for (int r = 0; r < 4; ++r) {
                float s1 = 0.f, s2 = 0.f;
                #pragma unroll
                for (int ct = 0; ct < 4; ++ct) {
                    s1 += acc[ct][r] * wa1[ct];
                    s2 += acc[ct][r] * wa2[ct];
                }
                #pragma unroll
                for (int off = 1; off < 16; off <<= 1) {
                    s1 += __shfl_xor(s1, off);
                    s2 += __shfl_xor(s2, off);
                }
                int row = rbase + r;
                if (cl == 0 && row < N_NODES) {
                    a_src[row] = s1;
                    a_dst[row] = s2;
                }
            }
        }
    }

    grid.sync();

    // ======== phase 4: per-bin LDS-CSR build + aggregate (782 blocks) ========
    if (g < NBINS_USED) {
        const int b     = g;
        const int node0 = b * BINW;
        const int estart = binStartG[b];
        const int ecnt   = min(binTotal[b], LCSRCAP);

        if (t < BINW) {
            sh.ag.cnt[t] = 0;
            int gd = node0 + t;
            sh.ag.adl[t] = (gd < N_NODES) ? a_dst[gd] : 0.f;
        }
        __syncthreads();

        for (int i = t; i < ecnt; i += 256)
            atomicAdd(&sh.ag.cnt[ebuf[estart + i] & (BINW - 1)], 1);
        __syncthreads();

        if (t < 64) {
            int v = sh.ag.cnt[t];
            int incl = v;
            #pragma unroll
            for (int off = 1; off < 64; off <<= 1) {
                int u = __shfl_up(incl, off);
                if (t >= off) incl += u;
            }
            int e = incl - v;
            sh.ag.rb[t] = e;
            sh.ag.cur[t] = e;
        }
        __syncthreads();

        for (int i = t; i < ecnt; i += 256) {
            int pk = ebuf[estart + i];
            int ld = pk & (BINW - 1);
            int s  = pk >> 6;
            float u = a_src[s] + sh.ag.adl[ld];
            u = u > 0.f ? u : 0.01f * u;
            float w = __expf(u);
            int p2 = atomicAdd(&sh.ag.cur[ld], 1);
            sh.ag.lcsr[p2] = pack_sw(s, w);
        }
        __syncthreads();

        // aggregate: 4 waves x 16 nodes each; 8 edges x 8 lanes x f16x8
        const int grp = lane >> 3;
        const int cl8 = lane & 7;
        for (int i = 0; i < 16; ++i) {
            const int ld   = i * 4 + wid;
            const int node = node0 + ld;
            if (node >= N_NODES) continue;
            const int beg = sh.ag.rb[ld];
            const int deg = sh.ag.cnt[ld];

            float dn = 0.0f;
            float acc8[8] = {0.f, 0.f, 0.f, 0.f, 0.f, 0.f, 0.f, 0.f};

            for (int cb = 0; cb < deg; cb += 64) {
                const int rem = min(deg - cb, 64);
                if (lane < rem) dn += unpack_w(sh.ag.lcsr[beg + cb + lane]);
                const int kmax = (rem + 7) & ~7;
                for (int k = 0; k < kmax; k += 8) {
                    const int ei = k + grp;
                    unsigned int pe = (ei < rem) ? sh.ag.lcsr[beg + cb + ei] : 0u;
                    int   sk = (int)(pe >> 16);
                    float wk = unpack_w(pe);
                    f16x8 zv = *(const f16x8*)&z[(size_t)sk * OUT_DIM + cl8 * 8];
                    #pragma unroll
                    for (int j = 0; j < 8; ++j)
                        acc8[j] = fmaf(wk, (float)zv[j], acc8[j]);
                }
            }

            #pragma unroll
            for (int off = 32; off; off >>= 1) dn += __shfl_xor(dn, off);
            #pragma unroll
            for (int off = 8; off < 64; off <<= 1) {
                #pragma unroll
                for (int j = 0; j < 8; ++j)
                    acc8[j] += __shfl_xor(acc8[j], off);
            }

            if (lane < 8) {
                float inv = 1.0f / fmaxf(dn, 1e-16f);
                float4 o0 = make_float4(acc8[0] * inv, acc8[1] * inv, acc8[2] * inv, acc8[3] * inv);
                float4 o1 = make_float4(acc8[4] * inv, acc8[5] * inv, acc8[6] * inv, acc8[7] * inv);
                *(float4*)&out[(size_t)node * OUT_DIM + lane * 8]     = o0;
                *(float4*)&out[(size_t)node * OUT_DIM + lane * 8 + 4] = o1;
            }
        }
    }
}

// ---------------- launch ----------------

extern "C" void kernel_launch(void* const* d_in, const int* in_sizes, int n_in,
                              void* d_out, int out_size, void* d_ws, size_t ws_size,
                              hipStream_t stream) {
    const float* h      = (const float*)d_in[0];
    const float* W_fc   = (const float*)d_in[1];
    const float* W_attn = (const float*)d_in[2];
    const int*   src    = (const int*)d_in[3];
    const int*   dst    = (const int*)d_in[4];
    float* out = (float*)d_out;

    // workspace layout
    f16*   z        = (f16*)d_ws;                             // N*64 f16 (6.4 MB)
    f16*   Wh       = z + (size_t)N_NODES * OUT_DIM;          // 64*256 f16
    float* a_src    = (float*)(Wh + OUT_DIM * IN_DIM);        // N
    float* a_dst    = a_src + N_NODES;                        // N
    int*   base     = (int*)(a_dst + N_NODES);                // NCHUNK*NBINS (3.7 MB)
    int*   binTotal = base + (size_t)NCHUNK * NBINS;          // 1024
    int*   binStart = binTotal + NBINS;                       // 1024
    int*   ebuf     = binStart + NBINS;                       // E

    void* args[] = { (void*)&h, (void*)&W_fc, (void*)&W_attn, (void*)&src, (void*)&dst,
                     (void*)&z, (void*)&Wh, (void*)&a_src, (void*)&a_dst,
                     (void*)&base, (void*)&binTotal, (void*)&binStart, (void*)&ebuf,
                     (void*)&out };
    hipLaunchCooperativeKernel((const void*)k_all, dim3(GRID), dim3(256), args, 0, stream);
}